// Round 1
// baseline (3571.579 us; speedup 1.0000x reference)
//
#include <hip/hip_runtime.h>
#include <math.h>

#define ALPHA_LRELU 0.2f
#define NEGV (-1e15f)

constexpr int Bc = 2, Nn = 2048, Ff = 256, Hh = 8, Oo = 32;

// ---------------------------------------------------------------------------
// GEMM: C[b,g,n,o] = sum_f A[b,n,f] * W[g,f,o]
// Naive per-element dot; W loads coalesced over o, A broadcast. L1/L2-served.
// ---------------------------------------------------------------------------
__global__ __launch_bounds__(256) void gemm_kernel(
    const float* __restrict__ A, const float* __restrict__ W,
    float* __restrict__ C, int G, int Ofull) {
    int idx = blockIdx.x * 256 + threadIdx.x;
    int o = idx % Ofull;
    int n = (idx / Ofull) % Nn;
    int g = (idx / (Ofull * Nn)) % G;
    int b = idx / (Ofull * Nn * G);
    const float* a = A + ((size_t)b * Nn + n) * Ff;
    const float* w = W + (size_t)g * Ff * Ofull + o;
    float acc = 0.f;
#pragma unroll 8
    for (int f = 0; f < Ff; ++f)
        acc += a[f] * w[(size_t)f * Ofull];
    C[idx] = acc;
}

// ---------------------------------------------------------------------------
// s1[b,g,n] = sum_o Wh[b,g,n,o]*a1[g,o];  s2 likewise with a2.
// a1 = pa + g*2*Ofull, a2 = a1 + Ofull.
// ---------------------------------------------------------------------------
__global__ __launch_bounds__(256) void s_kernel(
    const float* __restrict__ Wh, const float* __restrict__ pa,
    float* __restrict__ s1, float* __restrict__ s2, int G, int Ofull) {
    int idx = blockIdx.x * 256 + threadIdx.x;
    if (idx >= Bc * G * Nn) return;
    int g = (idx / Nn) % G;
    const float* row = Wh + (size_t)idx * Ofull;
    const float* a1 = pa + (size_t)g * 2 * Ofull;
    const float* a2 = a1 + Ofull;
    float x1 = 0.f, x2 = 0.f;
    for (int o = 0; o < Ofull; ++o) {
        float v = row[o];
        x1 += v * a1[o];
        x2 += v * a2[o];
    }
    s1[idx] = x1;
    s2[idx] = x2;
}

// ---------------------------------------------------------------------------
// Fused masked-softmax attention + aggregation (flash-style, fp32).
//   e_ij = lrelu(s1_i + s2_j), masked by adj; att = softmax_j; out = elu(att@Wh)
// Block: 256 threads, TI rows x O_TILE cols of output, chunks of CJ over j.
//   thread t: o_l = t%O_TILE, grp = t/O_TILE; owns rows grp + GC*r.
// DOUBLE_ELU: out-GAT applies elu twice (once in _gat_heads, once after).
// dst[b, i, g*Ofull + o0 + o_l]  (row stride Ff) -> handles the head transpose.
// ---------------------------------------------------------------------------
template <int O_TILE, int TI, int CJ, bool DOUBLE_ELU>
__global__ __launch_bounds__(256) void attn_kernel(
    const float* __restrict__ Wh, const float* __restrict__ s1,
    const float* __restrict__ s2, const int* __restrict__ adj,
    float* __restrict__ dst, int G, int Ofull) {
    constexpr int GC = 256 / O_TILE;  // thread groups over rows (MAC phase)
    constexpr int RP = TI / GC;       // rows per thread (MAC phase)
    constexpr int EG = 256 / CJ;      // row groups (e phase)
    constexpr int RE = TI / EG;       // rows per thread (e phase)

    __shared__ float wh_lds[CJ][O_TILE];
    __shared__ float p_lds[TI][CJ + 1];
    __shared__ float s1_t[TI], m_run[TI], l_run[TI], alpha_t[TI], s2_t[CJ];

    int t = threadIdx.x;
    int i0 = blockIdx.x * TI;
    int o0 = blockIdx.y * O_TILE;
    int bg = blockIdx.z;
    int b = bg / G, g = bg % G;

    const float* wh_base = Wh + (size_t)(b * G + g) * Nn * Ofull;
    const float* s1p = s1 + (size_t)(b * G + g) * Nn + i0;
    const float* s2p = s2 + (size_t)(b * G + g) * Nn;
    const int* adj_b = adj + (size_t)b * Nn * Nn;

    if (t < TI) {
        s1_t[t] = s1p[t];
        m_run[t] = -INFINITY;
        l_run[t] = 0.f;
    }

    int o_l = t % O_TILE;
    int grp = t / O_TILE;
    int j_e = t % CJ;
    int eg = t / CJ;

    float acc[RP];
#pragma unroll
    for (int r = 0; r < RP; ++r) acc[r] = 0.f;

    __syncthreads();

    for (int j0 = 0; j0 < Nn; j0 += CJ) {
        // stage Wh chunk (coalesced)
#pragma unroll
        for (int k = 0; k < CJ * O_TILE / 256; ++k) {
            int idx = t + k * 256;
            int jj = idx / O_TILE, oo = idx % O_TILE;
            wh_lds[jj][oo] = wh_base[(size_t)(j0 + jj) * Ofull + o0 + oo];
        }
        if (t < CJ) s2_t[t] = s2p[j0 + t];
        __syncthreads();

        // e-phase: logits into p_lds
#pragma unroll
        for (int r = 0; r < RE; ++r) {
            int i = eg + EG * r;
            float e = s1_t[i] + s2_t[j_e];
            e = e > 0.f ? e : ALPHA_LRELU * e;
            int m = adj_b[(size_t)(i0 + i) * Nn + j0 + j_e];
            p_lds[i][j_e] = m ? e : NEGV;
        }
        __syncthreads();

        // per-row chunk max -> new running max + rescale factor
        if (t < TI) {
            float mx = -INFINITY;
            for (int j = 0; j < CJ; ++j) mx = fmaxf(mx, p_lds[t][j]);
            float mn = fmaxf(m_run[t], mx);
            alpha_t[t] = __expf(m_run[t] - mn);
            m_run[t] = mn;
        }
        __syncthreads();

        // p-phase: exponentiate in place
#pragma unroll
        for (int r = 0; r < RE; ++r) {
            int i = eg + EG * r;
            p_lds[i][j_e] = __expf(p_lds[i][j_e] - m_run[i]);
        }
        __syncthreads();

        // MAC: acc = acc*alpha + P_chunk @ Wh_chunk
#pragma unroll
        for (int r = 0; r < RP; ++r) acc[r] *= alpha_t[grp + GC * r];
        for (int j = 0; j < CJ; ++j) {
            float wv = wh_lds[j][o_l];
#pragma unroll
            for (int r = 0; r < RP; ++r)
                acc[r] += p_lds[grp + GC * r][j] * wv;
        }
        __syncthreads();

        // l update
        if (t < TI) {
            float sm = 0.f;
            for (int j = 0; j < CJ; ++j) sm += p_lds[t][j];
            l_run[t] = l_run[t] * alpha_t[t] + sm;
        }
        __syncthreads();
    }

    // epilogue: normalize, elu, (elu again for out-GAT), store
#pragma unroll
    for (int r = 0; r < RP; ++r) {
        int i = grp + GC * r;
        float v = acc[r] / l_run[i];
        v = v > 0.f ? v : __expf(v) - 1.f;
        if (DOUBLE_ELU) v = v > 0.f ? v : __expf(v) - 1.f;
        dst[((size_t)b * Nn + (i0 + i)) * Ff + g * Ofull + o0 + o_l] = v;
    }
}

// ---------------------------------------------------------------------------
extern "C" void kernel_launch(void* const* d_in, const int* in_sizes, int n_in,
                              void* d_out, int out_size, void* d_ws, size_t ws_size,
                              hipStream_t stream) {
    const float* x = (const float*)d_in[0];
    const int* adj = (const int*)d_in[1];
    const float* W_heads = (const float*)d_in[2];
    const float* a_heads = (const float*)d_in[3];
    const float* W_out = (const float*)d_in[4];
    const float* a_out = (const float*)d_in[5];
    float* out = (float*)d_out;

    float* ws = (float*)d_ws;
    const size_t M = (size_t)Bc * Nn * Ff;  // 1,048,576 elements
    float* h_cur = ws;          // [B,N,F]
    float* Wh = ws + M;         // [B,H,N,O] or [B,N,F] (same size)
    float* h_tmp = ws + 2 * M;  // [B,N,F]
    float* s1 = ws + 3 * M;     // [B,H,N]
    float* s2 = s1 + (size_t)Bc * Hh * Nn;

    for (int l = 0; l < 3; ++l) {
        const float* hin = (l == 0) ? x : h_cur;

        // ---- head GAT: H=8, O=32 ----
        gemm_kernel<<<(Bc * Hh * Nn * Oo) / 256, 256, 0, stream>>>(
            hin, W_heads + (size_t)l * Hh * Ff * Oo, Wh, Hh, Oo);
        s_kernel<<<(Bc * Hh * Nn) / 256, 256, 0, stream>>>(
            Wh, a_heads + (size_t)l * Hh * 2 * Oo, s1, s2, Hh, Oo);
        attn_kernel<32, 32, 64, false><<<dim3(Nn / 32, 1, Bc * Hh), 256, 0, stream>>>(
            Wh, s1, s2, adj, h_tmp, Hh, Oo);

        // ---- out GAT: H=1, O=F=256 ----
        gemm_kernel<<<(Bc * Nn * Ff) / 256, 256, 0, stream>>>(
            h_tmp, W_out + (size_t)l * Ff * Ff, Wh, 1, Ff);
        s_kernel<<<(Bc * Nn + 255) / 256, 256, 0, stream>>>(
            Wh, a_out + (size_t)l * 2 * Ff, s1, s2, 1, Ff);
        float* dstp = (l == 2) ? out : h_cur;
        attn_kernel<128, 16, 32, true><<<dim3(Nn / 16, 2, Bc), 256, 0, stream>>>(
            Wh, s1, s2, adj, dstp, 1, Ff);
    }
}

// Round 2
// 774.000 us; speedup vs baseline: 4.6144x; 4.6144x over previous
//
#include <hip/hip_runtime.h>
#include <math.h>

#define ALPHA_LRELU 0.2f
#define NEGV (-1e15f)
#define ESHIFT 6.0f

constexpr int Bc = 2, Nn = 2048, Ff = 256, Hh = 8, Oo = 32;

typedef _Float16 f16;
typedef f16 f16x8 __attribute__((ext_vector_type(8)));
typedef float f32x4 __attribute__((ext_vector_type(4)));

// ---------------------------------------------------------------------------
// Pack adj (int32) into a bitmask: mask64[b][i][w] bit l = adj[b][i][w*64+l]>0
// ---------------------------------------------------------------------------
__global__ __launch_bounds__(256) void pack_kernel(
    const int* __restrict__ adj, unsigned long long* __restrict__ mask) {
    int idx = blockIdx.x * 256 + threadIdx.x;
    unsigned long long b = __ballot(adj[idx] != 0);
    if ((threadIdx.x & 63) == 0) mask[idx >> 6] = b;
}

// ---------------------------------------------------------------------------
// GEMM: C[b,g,n,o] = sum_f A[b,n,f] * W[g,f,o]; also emits CT fp16 transposed
// CT[b,g,o,n] for the MFMA attention B-operand.
// ---------------------------------------------------------------------------
__global__ __launch_bounds__(256) void gemm_kernel(
    const float* __restrict__ A, const float* __restrict__ W,
    float* __restrict__ C, f16* __restrict__ CT, int G, int Ofull) {
    int idx = blockIdx.x * 256 + threadIdx.x;
    int o = idx % Ofull;
    int n = (idx / Ofull) % Nn;
    int g = (idx / (Ofull * Nn)) % G;
    int b = idx / (Ofull * Nn * G);
    const float* a = A + ((size_t)b * Nn + n) * Ff;
    const float* w = W + (size_t)g * Ff * Ofull + o;
    float acc = 0.f;
#pragma unroll 8
    for (int f = 0; f < Ff; ++f)
        acc += a[f] * w[(size_t)f * Ofull];
    C[idx] = acc;
    CT[((size_t)(b * G + g) * Ofull + o) * Nn + n] = (f16)acc;
}

// ---------------------------------------------------------------------------
// s1/s2: wave per row. s1[r] = sum_o Wh[r,o]*a1[g,o], s2 likewise.
// ---------------------------------------------------------------------------
__global__ __launch_bounds__(256) void s_kernel(
    const float* __restrict__ Wh, const float* __restrict__ pa,
    float* __restrict__ s1, float* __restrict__ s2, int G, int Ofull) {
    int wid = (blockIdx.x * 256 + threadIdx.x) >> 6;  // row over B*G*N
    int lane = threadIdx.x & 63;
    int g = (wid / Nn) % G;
    const float* row = Wh + (size_t)wid * Ofull;
    const float* a1 = pa + (size_t)g * 2 * Ofull;
    const float* a2 = a1 + Ofull;
    float x1 = 0.f, x2 = 0.f;
    for (int o = lane; o < Ofull; o += 64) {
        float v = row[o];
        x1 += v * a1[o];
        x2 += v * a2[o];
    }
#pragma unroll
    for (int s = 32; s > 0; s >>= 1) {
        x1 += __shfl_xor(x1, s);
        x2 += __shfl_xor(x2, s);
    }
    if (lane == 0) { s1[wid] = x1; s2[wid] = x2; }
}

// ---------------------------------------------------------------------------
// MFMA attention: block = 32 rows x 32 o-cols, 4 waves (wave = 16x16 tile).
// Chunks of CJ=64 over j: e-phase (256 thr x 8 elems -> fp16 P in LDS),
// then 2 mfma_f32_16x16x32_f16 per wave. No online softmax: p=exp(e-6),
// masked -> 0; l accumulated in registers. B-frags read from global WhT fp16.
// ---------------------------------------------------------------------------
template <bool DOUBLE_ELU>
__global__ __launch_bounds__(256) void attn_kernel(
    const f16* __restrict__ WhT, const float* __restrict__ s1,
    const float* __restrict__ s2, const unsigned long long* __restrict__ mask,
    float* __restrict__ dst, int G, int Ofull) {
    constexpr int TI = 32, PSTR = 72;  // P row stride (f16): 144B, 16B-aligned
    __shared__ f16 P[TI * PSTR];
    __shared__ float s2_l[Nn];
    __shared__ float l_l[TI];

    int t = threadIdx.x;
    int i0 = blockIdx.x * TI;
    int bg = blockIdx.z;
    int b = bg / G, g = bg % G;
    int o_blk = blockIdx.y * 32;

    const f16* whT = WhT + ((size_t)(b * G + g) * Ofull + o_blk) * Nn;
    const float* s2p = s2 + (size_t)(b * G + g) * Nn;

    // stage s2 row into LDS (coalesced float4)
    for (int k = t; k < Nn / 4; k += 256)
        ((f32x4*)s2_l)[k] = ((const f32x4*)s2p)[k];

    // e-phase mapping: thread -> (row, 8-j group)
    int erow = t >> 3;
    int ejq = t & 7;
    float s1v = s1[(size_t)(b * G + g) * Nn + i0 + erow];
    const unsigned long long* mrow =
        mask + ((size_t)b * Nn + i0 + erow) * (Nn / 64);

    // mfma mapping: wave -> (16-row half, 16-col half)
    int w = t >> 6, lane = t & 63;
    int r0 = (w & 1) * 16, ob = (w >> 1) * 16;
    int am = lane & 15, aq = lane >> 4;
    f32x4 acc = {0.f, 0.f, 0.f, 0.f};
    float lacc = 0.f;

    __syncthreads();

    for (int c = 0; c < Nn / 64; ++c) {
        unsigned long long mw = mrow[c];
        unsigned bits = (unsigned)(mw >> (ejq * 8)) & 0xffu;
        f16x8 pv;
#pragma unroll
        for (int k = 0; k < 8; ++k) {
            float e = s1v + s2_l[c * 64 + ejq * 8 + k];
            e = e > 0.f ? e : ALPHA_LRELU * e;
            e = ((bits >> k) & 1u) ? e : NEGV;
            float p = __expf(e - ESHIFT);
            lacc += p;
            pv[k] = (f16)p;
        }
        *(f16x8*)&P[erow * PSTR + ejq * 8] = pv;
        __syncthreads();
#pragma unroll
        for (int s = 0; s < 2; ++s) {
            f16x8 afrag = *(const f16x8*)&P[(r0 + am) * PSTR + s * 32 + aq * 8];
            f16x8 bfrag = *(const f16x8*)&whT[(size_t)(ob + am) * Nn +
                                              c * 64 + s * 32 + aq * 8];
            acc = __builtin_amdgcn_mfma_f32_16x16x32_f16(afrag, bfrag, acc, 0, 0, 0);
        }
        __syncthreads();
    }

    // l: reduce 8 e-phase lanes per row (adjacent lanes), write to LDS
    lacc += __shfl_xor(lacc, 1);
    lacc += __shfl_xor(lacc, 2);
    lacc += __shfl_xor(lacc, 4);
    if (ejq == 0) l_l[erow] = lacc;
    __syncthreads();

    // epilogue: C/D layout col=lane&15, row=(lane>>4)*4+r
#pragma unroll
    for (int r = 0; r < 4; ++r) {
        int row = r0 + aq * 4 + r;
        float v = acc[r] / l_l[row];
        v = v > 0.f ? v : __expf(v) - 1.f;
        if (DOUBLE_ELU) v = v > 0.f ? v : __expf(v) - 1.f;
        dst[((size_t)b * Nn + i0 + row) * Ff + g * Ofull + o_blk + ob + am] = v;
    }
}

// ---------------------------------------------------------------------------
extern "C" void kernel_launch(void* const* d_in, const int* in_sizes, int n_in,
                              void* d_out, int out_size, void* d_ws, size_t ws_size,
                              hipStream_t stream) {
    const float* x = (const float*)d_in[0];
    const int* adj = (const int*)d_in[1];
    const float* W_heads = (const float*)d_in[2];
    const float* a_heads = (const float*)d_in[3];
    const float* W_out = (const float*)d_in[4];
    const float* a_out = (const float*)d_in[5];
    float* out = (float*)d_out;

    float* ws = (float*)d_ws;
    const size_t M = (size_t)Bc * Nn * Ff;  // 1,048,576
    float* h_cur = ws;                       // [B,N,F] fp32
    float* Wh = ws + M;                      // [B,G,N,O] fp32
    float* h_tmp = ws + 2 * M;               // [B,N,F] fp32
    f16* WhT = (f16*)(ws + 3 * M);           // [B,G,O,N] fp16 (512K floats)
    float* s1 = ws + 3 * M + M / 2;          // [B,G,N]
    float* s2 = s1 + (size_t)Bc * Hh * Nn;
    unsigned long long* mask =
        (unsigned long long*)(ws + 3 * M + M / 2 + 2 * ((size_t)Bc * Hh * Nn));

    pack_kernel<<<(Bc * Nn * Nn) / 256, 256, 0, stream>>>(adj, mask);

    for (int l = 0; l < 3; ++l) {
        const float* hin = (l == 0) ? x : h_cur;

        // ---- head GAT: G=8, O=32 ----
        gemm_kernel<<<(Bc * Hh * Nn * Oo) / 256, 256, 0, stream>>>(
            hin, W_heads + (size_t)l * Hh * Ff * Oo, Wh, WhT, Hh, Oo);
        s_kernel<<<(Bc * Hh * Nn) / 4, 256, 0, stream>>>(
            Wh, a_heads + (size_t)l * Hh * 2 * Oo, s1, s2, Hh, Oo);
        attn_kernel<false><<<dim3(Nn / 32, 1, Bc * Hh), 256, 0, stream>>>(
            WhT, s1, s2, mask, h_tmp, Hh, Oo);

        // ---- out GAT: G=1, O=F=256 ----
        gemm_kernel<<<(Bc * Nn * Ff) / 256, 256, 0, stream>>>(
            h_tmp, W_out + (size_t)l * Ff * Ff, Wh, WhT, 1, Ff);
        s_kernel<<<(Bc * Nn) / 4, 256, 0, stream>>>(
            Wh, a_out + (size_t)l * 2 * Ff, s1, s2, 1, Ff);
        float* dstp = (l == 2) ? out : h_cur;
        attn_kernel<true><<<dim3(Nn / 32, Ff / 32, Bc), 256, 0, stream>>>(
            WhT, s1, s2, mask, dstp, 1, Ff);
    }
}

// Round 3
// 426.082 us; speedup vs baseline: 8.3824x; 1.8166x over previous
//
#include <hip/hip_runtime.h>
#include <math.h>

#define ALPHA_LRELU 0.2f
#define NEGV (-1e15f)
#define ESHIFT 6.0f

constexpr int Bc = 2, Nn = 2048, Ff = 256, Hh = 8, Oo = 32;

typedef _Float16 f16;
typedef f16 f16x8 __attribute__((ext_vector_type(8)));
typedef f16 f16x4 __attribute__((ext_vector_type(4)));
typedef float f32x4 __attribute__((ext_vector_type(4)));

// ---------------------------------------------------------------------------
__global__ __launch_bounds__(256) void zero_kernel(float* __restrict__ p) {
    p[blockIdx.x * 256 + threadIdx.x] = 0.f;
}

// ---------------------------------------------------------------------------
// Pack adj (int32) into bitmask: mask[b][i][w] bit l = adj[b][i][w*64+l]>0
// ---------------------------------------------------------------------------
__global__ __launch_bounds__(256) void pack_kernel(
    const int* __restrict__ adj, unsigned long long* __restrict__ mask) {
    int idx = blockIdx.x * 256 + threadIdx.x;
    unsigned long long b = __ballot(adj[idx] != 0);
    if ((threadIdx.x & 63) == 0) mask[idx >> 6] = b;
}

// ---------------------------------------------------------------------------
// Tiled fp32 GEMM, fused epilogue:
//   acc = A[4096x256] @ Wcat[256x(G*Ofull)]   (Wcat[k, g*Ofull+o] = W[g,k,o])
//   emits CT fp16 [B,G,O,N] (attention B-operand), s1/s2 via atomics.
// 64x64 tile, BK=16, 256 threads, 4x4 register blocking, prefetch.
// ---------------------------------------------------------------------------
__global__ __launch_bounds__(256) void gemm_fused(
    const float* __restrict__ A, const float* __restrict__ W,
    const float* __restrict__ pa, f16* __restrict__ CT,
    float* __restrict__ s1, float* __restrict__ s2, int G, int Ofull) {
    constexpr int BM = 64, BN = 64, BK = 16;
    __shared__ float As[BK][BM + 4];  // transposed: As[k][m], 16B-aligned rows
    __shared__ float Bs[BK][BN + 4];
    const int K = Ff;
    int t = threadIdx.x;
    int m0 = blockIdx.x * BM, n0 = blockIdx.y * BN;
    int tn = t & 15, tm = t >> 4;
    int ar = t >> 2, ak = (t & 3) << 2;   // A stage: row m0+ar, k = ak..ak+3
    int wk = t >> 4, wn = (t & 15) << 2;  // W stage: k = wk, col n0+wn..+3
    int wg = (n0 + wn) / Ofull, wo = (n0 + wn) % Ofull;
    const float* Aptr = &A[(size_t)(m0 + ar) * K + ak];
    const float* Wptr = &W[((size_t)wg * K + wk) * Ofull + wo];

    f32x4 av = *(const f32x4*)Aptr;
    f32x4 wv = *(const f32x4*)Wptr;
    float acc[4][4] = {};

    for (int k0 = 0; k0 < K; k0 += BK) {
#pragma unroll
        for (int j = 0; j < 4; ++j) As[ak + j][ar] = av[j];
        *(f32x4*)&Bs[wk][wn] = wv;
        __syncthreads();
        if (k0 + BK < K) {
            av = *(const f32x4*)(Aptr + k0 + BK);
            wv = *(const f32x4*)(Wptr + (size_t)(k0 + BK) * Ofull);
        }
#pragma unroll
        for (int kk = 0; kk < BK; ++kk) {
            f32x4 af = *(const f32x4*)&As[kk][tm << 2];
            f32x4 bf = *(const f32x4*)&Bs[kk][tn << 2];
#pragma unroll
            for (int i = 0; i < 4; ++i)
#pragma unroll
                for (int j = 0; j < 4; ++j)
                    acc[i][j] = fmaf(af[i], bf[j], acc[i][j]);
        }
        __syncthreads();
    }

    // ---- epilogue ----
    int rm = m0 + (tm << 2);  // 4 rows rm..rm+3 (same b: 64 | Nn)
    int cn = n0 + (tn << 2);  // 4 cols (same g: 4 | 32)
    int b = rm / Nn, nn = rm % Nn;
    int g = cn / Ofull, o = cn % Ofull;
    size_t bg = (size_t)b * G + g;

    // CT[bg][o+j][nn..nn+3] (f16x4, 8B-aligned)
#pragma unroll
    for (int j = 0; j < 4; ++j) {
        f16x4 ct = {(f16)acc[0][j], (f16)acc[1][j], (f16)acc[2][j], (f16)acc[3][j]};
        *(f16x4*)&CT[(bg * Ofull + o + j) * Nn + nn] = ct;
    }

    // s1/s2 partial: dot cols with a1/a2, reduce over lanes sharing (row, g)
    const float* a1 = &pa[(size_t)g * 2 * Ofull + o];
    const float* a2 = a1 + Ofull;
    f32x4 a1v = *(const f32x4*)a1;
    f32x4 a2v = *(const f32x4*)a2;
    int gw = (Ofull >= 64) ? 16 : (Ofull >> 2);  // reduce width: 16 (out) / 8 (head)
#pragma unroll
    for (int i = 0; i < 4; ++i) {
        float p1 = acc[i][0] * a1v[0] + acc[i][1] * a1v[1] +
                   acc[i][2] * a1v[2] + acc[i][3] * a1v[3];
        float p2 = acc[i][0] * a2v[0] + acc[i][1] * a2v[1] +
                   acc[i][2] * a2v[2] + acc[i][3] * a2v[3];
        for (int s = 1; s < gw; s <<= 1) {
            p1 += __shfl_xor(p1, s);
            p2 += __shfl_xor(p2, s);
        }
        if ((tn & (gw - 1)) == 0) {
            size_t sidx = bg * Nn + nn + i;
            atomicAdd(&s1[sidx], p1);
            atomicAdd(&s2[sidx], p2);
        }
    }
}

// ---------------------------------------------------------------------------
// MFMA attention (unchanged from R2): block = 32 rows x 32 o-cols, 4 waves.
// ---------------------------------------------------------------------------
template <bool DOUBLE_ELU>
__global__ __launch_bounds__(256) void attn_kernel(
    const f16* __restrict__ WhT, const float* __restrict__ s1,
    const float* __restrict__ s2, const unsigned long long* __restrict__ mask,
    float* __restrict__ dst, int G, int Ofull) {
    constexpr int TI = 32, PSTR = 72;
    __shared__ f16 P[TI * PSTR];
    __shared__ float s2_l[Nn];
    __shared__ float l_l[TI];

    int t = threadIdx.x;
    int i0 = blockIdx.x * TI;
    int bg = blockIdx.z;
    int b = bg / G, g = bg % G;
    int o_blk = blockIdx.y * 32;

    const f16* whT = WhT + ((size_t)(b * G + g) * Ofull + o_blk) * Nn;
    const float* s2p = s2 + (size_t)(b * G + g) * Nn;

    for (int k = t; k < Nn / 4; k += 256)
        ((f32x4*)s2_l)[k] = ((const f32x4*)s2p)[k];

    int erow = t >> 3;
    int ejq = t & 7;
    float s1v = s1[(size_t)(b * G + g) * Nn + i0 + erow];
    const unsigned long long* mrow =
        mask + ((size_t)b * Nn + i0 + erow) * (Nn / 64);

    int w = t >> 6, lane = t & 63;
    int r0 = (w & 1) * 16, ob = (w >> 1) * 16;
    int am = lane & 15, aq = lane >> 4;
    f32x4 acc = {0.f, 0.f, 0.f, 0.f};
    float lacc = 0.f;

    __syncthreads();

    for (int c = 0; c < Nn / 64; ++c) {
        unsigned long long mw = mrow[c];
        unsigned bits = (unsigned)(mw >> (ejq * 8)) & 0xffu;
        f16x8 pv;
#pragma unroll
        for (int k = 0; k < 8; ++k) {
            float e = s1v + s2_l[c * 64 + ejq * 8 + k];
            e = e > 0.f ? e : ALPHA_LRELU * e;
            e = ((bits >> k) & 1u) ? e : NEGV;
            float p = __expf(e - ESHIFT);
            lacc += p;
            pv[k] = (f16)p;
        }
        *(f16x8*)&P[erow * PSTR + ejq * 8] = pv;
        __syncthreads();
#pragma unroll
        for (int s = 0; s < 2; ++s) {
            f16x8 afrag = *(const f16x8*)&P[(r0 + am) * PSTR + s * 32 + aq * 8];
            f16x8 bfrag = *(const f16x8*)&whT[(size_t)(ob + am) * Nn +
                                              c * 64 + s * 32 + aq * 8];
            acc = __builtin_amdgcn_mfma_f32_16x16x32_f16(afrag, bfrag, acc, 0, 0, 0);
        }
        __syncthreads();
    }

    lacc += __shfl_xor(lacc, 1);
    lacc += __shfl_xor(lacc, 2);
    lacc += __shfl_xor(lacc, 4);
    if (ejq == 0) l_l[erow] = lacc;
    __syncthreads();

#pragma unroll
    for (int r = 0; r < 4; ++r) {
        int row = r0 + aq * 4 + r;
        float v = acc[r] / l_l[row];
        v = v > 0.f ? v : __expf(v) - 1.f;
        if (DOUBLE_ELU) v = v > 0.f ? v : __expf(v) - 1.f;
        dst[((size_t)b * Nn + i0 + row) * Ff + g * Ofull + o_blk + ob + am] = v;
    }
}

// ---------------------------------------------------------------------------
extern "C" void kernel_launch(void* const* d_in, const int* in_sizes, int n_in,
                              void* d_out, int out_size, void* d_ws, size_t ws_size,
                              hipStream_t stream) {
    const float* x = (const float*)d_in[0];
    const int* adj = (const int*)d_in[1];
    const float* W_heads = (const float*)d_in[2];
    const float* a_heads = (const float*)d_in[3];
    const float* W_out = (const float*)d_in[4];
    const float* a_out = (const float*)d_in[5];
    float* out = (float*)d_out;

    float* ws = (float*)d_ws;
    const size_t M = (size_t)Bc * Nn * Ff;  // 1,048,576
    float* h_cur = ws;                      // [B,N,F] fp32
    float* h_tmp = ws + M;                  // [B,N,F] fp32
    f16* WhT = (f16*)(ws + 2 * M);          // [B,G,O,N] f16 (1M elems)
    unsigned long long* mask = (unsigned long long*)(ws + 2 * M + M / 2);  // 1 MB
    float* sbuf = ws + 2 * M + M / 2 + M / 4;
    const size_t SH = (size_t)Bc * Hh * Nn;  // 32768
    const size_t SO = (size_t)Bc * Nn;       // 4096
    // per layer: [s1_h, s2_h, s1_o, s2_o]; total 3*(2*SH+2*SO) = 221184
    const size_t SL = 2 * SH + 2 * SO;

    zero_kernel<<<(3 * SL) / 256, 256, 0, stream>>>(sbuf);
    pack_kernel<<<(Bc * Nn * Nn) / 256, 256, 0, stream>>>(adj, mask);

    for (int l = 0; l < 3; ++l) {
        const float* hin = (l == 0) ? x : h_cur;
        float* s1h = sbuf + l * SL;
        float* s2h = s1h + SH;
        float* s1o = s2h + SH;
        float* s2o = s1o + SO;

        // ---- head GAT: G=8, O=32 ----
        gemm_fused<<<dim3((Bc * Nn) / 64, (Hh * Oo) / 64), 256, 0, stream>>>(
            hin, W_heads + (size_t)l * Hh * Ff * Oo,
            a_heads + (size_t)l * Hh * 2 * Oo, WhT, s1h, s2h, Hh, Oo);
        attn_kernel<false><<<dim3(Nn / 32, 1, Bc * Hh), 256, 0, stream>>>(
            WhT, s1h, s2h, mask, h_tmp, Hh, Oo);

        // ---- out GAT: G=1, O=F=256 ----
        gemm_fused<<<dim3((Bc * Nn) / 64, Ff / 64), 256, 0, stream>>>(
            h_tmp, W_out + (size_t)l * Ff * Ff,
            a_out + (size_t)l * 2 * Ff, WhT, s1o, s2o, 1, Ff);
        float* dstp = (l == 2) ? out : h_cur;
        attn_kernel<true><<<dim3(Nn / 32, Ff / 32, Bc), 256, 0, stream>>>(
            WhT, s1o, s2o, mask, dstp, 1, Ff);
    }
}

// Round 4
// 352.576 us; speedup vs baseline: 10.1299x; 1.2085x over previous
//
#include <hip/hip_runtime.h>
#include <math.h>

#if __has_builtin(__builtin_amdgcn_exp2f)
#define EXP2(x) __builtin_amdgcn_exp2f(x)
#else
#define EXP2(x) exp2f(x)
#endif

#define ALPHA_LRELU 0.2f
#define LOG2E 1.4426950408889634f
#define ESHIFT 6.0f
#define BIGM 1024.0f  // mask offset in exp2 domain: bit=0 -> arg < -1000 -> p=0

constexpr int Bc = 2, Nn = 2048, Ff = 256, Hh = 8, Oo = 32;
constexpr int NC = Nn / 64;  // j-chunks of 64

typedef _Float16 f16;
typedef f16 f16x8 __attribute__((ext_vector_type(8)));
typedef f16 f16x4 __attribute__((ext_vector_type(4)));
typedef f16 f16x2 __attribute__((ext_vector_type(2)));
typedef float f32x4 __attribute__((ext_vector_type(4)));
typedef float f32x2 __attribute__((ext_vector_type(2)));
typedef unsigned long long u64;

__global__ __launch_bounds__(256) void zero_kernel(float* __restrict__ p) {
    p[blockIdx.x * 256 + threadIdx.x] = 0.f;
}

// ---------------------------------------------------------------------------
// adj -> bitmask
// ---------------------------------------------------------------------------
__global__ __launch_bounds__(256) void pack_kernel(
    const int* __restrict__ adj, u64* __restrict__ mask) {
    int idx = blockIdx.x * 256 + threadIdx.x;
    u64 b = __ballot(adj[idx] != 0);
    if ((threadIdx.x & 63) == 0) mask[idx >> 6] = b;
}

// ---------------------------------------------------------------------------
// Pre-transpose + cast weights: WT[y][c][k] f16, y = l*2+stage.
// stage0: W_heads[l][c>>5][k][c&31]; stage1: W_out[l][k][c].
// ---------------------------------------------------------------------------
__global__ __launch_bounds__(256) void wt_kernel(
    const float* __restrict__ W_heads, const float* __restrict__ W_out,
    f16* __restrict__ WT) {
    int t = threadIdx.x;
    int y = blockIdx.y;
    int l = y >> 1, st = y & 1;
    int c = blockIdx.x * 4 + (t >> 6);
    int k0 = (t & 63) * 4;
    const float* src;
    int stride;
    if (st == 0) {
        src = W_heads + (((size_t)l * Hh + (c >> 5)) * Ff) * Oo + (c & 31);
        stride = Oo;
    } else {
        src = W_out + (size_t)l * Ff * Ff + c;
        stride = Ff;
    }
    f16x4 v;
#pragma unroll
    for (int i = 0; i < 4; ++i) v[i] = (f16)src[(size_t)(k0 + i) * stride];
    *(f16x4*)&WT[((size_t)y * Ff + c) * Ff + k0] = v;
}

// ---------------------------------------------------------------------------
// MFMA GEMM: C[4096 x 256] = A[4096 x 256] @ WT^T, A fp32 -> f16 staged in LDS,
// B-frags straight from global WT f16 (L2-hot). 32x64 tile, 4 waves, BK=32,
// single barrier/iter. Fused epilogue: CT f16 [bg][o][n] + s1/s2 atomics.
// ---------------------------------------------------------------------------
__global__ __launch_bounds__(256) void gemm_mfma(
    const float* __restrict__ A, const f16* __restrict__ WT,
    const float* __restrict__ pa, f16* __restrict__ CT,
    float* __restrict__ s1, float* __restrict__ s2, int G, int Ofull,
    int oshift) {
    constexpr int ASTR = 40;  // f16 row stride (80B)
    __shared__ f16 As[2][32 * ASTR];
    int t = threadIdx.x;
    int m0 = blockIdx.x * 32;
    int n0 = blockIdx.y * 64;
    int sm = t >> 3, skq = (t & 7) * 4;  // staging: row sm, k-offset skq
    const float* aptr = &A[(size_t)(m0 + sm) * Ff + skq];
    int w = t >> 6, lane = t & 63;
    int am = lane & 15, aq = lane >> 4;
    int ti = w & 1;           // row half
    int c0 = (w >> 1) * 32;   // col base within block
    const f16* b0p = &WT[(size_t)(n0 + c0 + am) * Ff + aq * 8];
    const f16* b1p = &WT[(size_t)(n0 + c0 + 16 + am) * Ff + aq * 8];

    f32x4 av = *(const f32x4*)aptr;
    f16x8 bc0 = *(const f16x8*)b0p;
    f16x8 bc1 = *(const f16x8*)b1p;
    f32x4 acc0 = {0.f, 0.f, 0.f, 0.f}, acc1 = {0.f, 0.f, 0.f, 0.f};

    for (int ki = 0; ki < 8; ++ki) {
        f16x4 a4;
#pragma unroll
        for (int i = 0; i < 4; ++i) a4[i] = (f16)av[i];
        *(f16x4*)&As[ki & 1][sm * ASTR + skq] = a4;
        int kn = (ki < 7) ? (ki + 1) * 32 : 0;
        f32x4 avn = *(const f32x4*)(aptr + kn);
        f16x8 bn0 = *(const f16x8*)(b0p + kn);
        f16x8 bn1 = *(const f16x8*)(b1p + kn);
        __syncthreads();
        const f16* ap = &As[ki & 1][(ti * 16 + am) * ASTR + aq * 8];
        f16x8 afrag = *(const f16x8*)ap;
        acc0 = __builtin_amdgcn_mfma_f32_16x16x32_f16(afrag, bc0, acc0, 0, 0, 0);
        acc1 = __builtin_amdgcn_mfma_f32_16x16x32_f16(afrag, bc1, acc1, 0, 0, 0);
        av = avn; bc0 = bn0; bc1 = bn1;
        __syncthreads();
    }

    // ---- epilogue ----
    int b = m0 >> 11;
    int nnb = (m0 & 2047) + ti * 16 + aq * 4;  // 4 consecutive rows
    int colb = n0 + c0;                        // wave's 32 cols: colb + tj*16 + am
    int g = colb >> oshift;                    // uniform per wave
    size_t bg = (size_t)b * G + g;
    int ob0 = (colb & (Ofull - 1)) + am, ob1 = ob0 + 16;

    f16x4 c40, c41;
#pragma unroll
    for (int e = 0; e < 4; ++e) { c40[e] = (f16)acc0[e]; c41[e] = (f16)acc1[e]; }
    *(f16x4*)&CT[(bg * Ofull + ob0) * Nn + nnb] = c40;
    *(f16x4*)&CT[(bg * Ofull + ob1) * Nn + nnb] = c41;

    const float* a1p = pa + 2 * (size_t)g * Ofull;
    float a10 = a1p[ob0], a11 = a1p[ob1];
    float a20 = a1p[Ofull + ob0], a21 = a1p[Ofull + ob1];
#pragma unroll
    for (int e = 0; e < 4; ++e) {
        float p1 = acc0[e] * a10 + acc1[e] * a11;
        float p2 = acc0[e] * a20 + acc1[e] * a21;
#pragma unroll
        for (int s = 1; s < 16; s <<= 1) {
            p1 += __shfl_xor(p1, s);
            p2 += __shfl_xor(p2, s);
        }
        if (am == 0) {
            size_t sidx = bg * Nn + nnb + e;
            atomicAdd(&s1[sidx], p1);
            atomicAdd(&s2[sidx], p2);
        }
    }
}

// ---------------------------------------------------------------------------
// Head attention: 32 rows x 32 cols per block, 4 waves, P double-buffered,
// one barrier per 64-j chunk, whT frags prefetched a full chunk ahead.
// ---------------------------------------------------------------------------
__global__ __launch_bounds__(256) void attn_head(
    const f16* __restrict__ WhT, const float* __restrict__ s1,
    const float* __restrict__ s2, const u64* __restrict__ mask,
    float* __restrict__ dst) {
    constexpr int TI = 32, PSTR = 72;
    __shared__ f16 P[2][TI * PSTR];
    __shared__ float s2_l[Nn];
    __shared__ float l_l[TI];
    constexpr float C0 = -ESHIFT * LOG2E - BIGM;

    int t = threadIdx.x;
    int i0 = blockIdx.x * TI;
    int bg = blockIdx.z;
    int b = bg >> 3, g = bg & 7;
    const f16* whT = WhT + (size_t)bg * Oo * Nn;
    const float* s2p = s2 + (size_t)bg * Nn;
    ((f32x4*)s2_l)[t] = ((const f32x4*)s2p)[t];
    ((f32x4*)s2_l)[t + 256] = ((const f32x4*)s2p)[t + 256];

    int erow = t >> 3, ejq = t & 7;
    float s1v = s1[(size_t)bg * Nn + i0 + erow];
    const u64* mrow = mask + ((size_t)b * Nn + i0 + erow) * (Nn / 64);

    int w = t >> 6, lane = t & 63;
    int r0 = (w & 1) * 16, ob = (w >> 1) * 16;
    int am = lane & 15, aq = lane >> 4;
    const f16* bbase = whT + (size_t)(ob + am) * Nn + aq * 8;

    f32x4 acc = {0.f, 0.f, 0.f, 0.f};
    float lacc = 0.f;
    f16x8 bc0 = *(const f16x8*)bbase;
    f16x8 bc1 = *(const f16x8*)(bbase + 32);
    u64 mw = mrow[0];
    __syncthreads();  // s2_l ready

    {  // e-phase chunk 0 -> P[0]
        f32x4 sv0 = *(const f32x4*)&s2_l[ejq * 8];
        f32x4 sv1 = *(const f32x4*)&s2_l[ejq * 8 + 4];
        f16x8 pv;
#pragma unroll
        for (int k = 0; k < 8; ++k) {
            float xv = s1v + (k < 4 ? sv0[k & 3] : sv1[k & 3]);
            float lr = fmaxf(xv, ALPHA_LRELU * xv);
            float bitf = (float)((unsigned)(mw >> (ejq * 8 + k)) & 1u);
            float p = EXP2(fmaf(bitf, BIGM, fmaf(lr, LOG2E, C0)));
            lacc += p;
            pv[k] = (f16)p;
        }
        *(f16x8*)&P[0][erow * PSTR + ejq * 8] = pv;
    }
    u64 mwn = mrow[1];

    for (int c = 0; c < NC; ++c) {
        __syncthreads();  // P[c&1] ready; buffer (c+1)&1 free
        int cn = (c + 1 < NC) ? c + 1 : 0;
        f16x8 bn0 = *(const f16x8*)(bbase + (size_t)cn * 64);
        f16x8 bn1 = *(const f16x8*)(bbase + (size_t)cn * 64 + 32);
        if (c + 1 < NC) {
            int jb = (c + 1) * 64 + ejq * 8;
            f32x4 sv0 = *(const f32x4*)&s2_l[jb];
            f32x4 sv1 = *(const f32x4*)&s2_l[jb + 4];
            f16x8 pv;
#pragma unroll
            for (int k = 0; k < 8; ++k) {
                float xv = s1v + (k < 4 ? sv0[k & 3] : sv1[k & 3]);
                float lr = fmaxf(xv, ALPHA_LRELU * xv);
                float bitf = (float)((unsigned)(mwn >> (ejq * 8 + k)) & 1u);
                float p = EXP2(fmaf(bitf, BIGM, fmaf(lr, LOG2E, C0)));
                lacc += p;
                pv[k] = (f16)p;
            }
            *(f16x8*)&P[(c + 1) & 1][erow * PSTR + ejq * 8] = pv;
            mwn = mrow[(c + 2 < NC) ? c + 2 : NC - 1];
        }
        const f16* pb = &P[c & 1][(r0 + am) * PSTR + aq * 8];
        f16x8 a0 = *(const f16x8*)pb;
        f16x8 a1 = *(const f16x8*)(pb + 32);
        acc = __builtin_amdgcn_mfma_f32_16x16x32_f16(a0, bc0, acc, 0, 0, 0);
        acc = __builtin_amdgcn_mfma_f32_16x16x32_f16(a1, bc1, acc, 0, 0, 0);
        bc0 = bn0; bc1 = bn1;
    }

    lacc += __shfl_xor(lacc, 1);
    lacc += __shfl_xor(lacc, 2);
    lacc += __shfl_xor(lacc, 4);
    if (ejq == 0) l_l[erow] = lacc;
    __syncthreads();

#pragma unroll
    for (int r = 0; r < 4; ++r) {
        int row = r0 + aq * 4 + r;
        float v = acc[r] / l_l[row];
        v = v > 0.f ? v : __expf(v) - 1.f;
        dst[((size_t)b * Nn + i0 + row) * Ff + g * Oo + ob + am] = v;
    }
}

// ---------------------------------------------------------------------------
// Out attention: 16 rows x ALL 256 cols per block (8 waves, 512 thr) ->
// e-phase computed once (8x dedup vs R3). Double ELU.
// ---------------------------------------------------------------------------
__global__ __launch_bounds__(512) void attn_out(
    const f16* __restrict__ WhT, const float* __restrict__ s1,
    const float* __restrict__ s2, const u64* __restrict__ mask,
    float* __restrict__ dst) {
    constexpr int TI = 16, PSTR = 72;
    __shared__ f16 P[2][TI * PSTR];
    __shared__ float s2_l[Nn];
    __shared__ float l_l[TI];
    constexpr float C0 = -ESHIFT * LOG2E - BIGM;

    int t = threadIdx.x;
    int i0 = blockIdx.x * TI;
    int b = blockIdx.z;
    const f16* whT = WhT + (size_t)b * Ff * Nn;
    const float* s2p = s2 + (size_t)b * Nn;
    ((f32x4*)s2_l)[t] = ((const f32x4*)s2p)[t];

    int erow = t >> 5, ejq = t & 31;
    float s1v = s1[(size_t)b * Nn + i0 + erow];
    const u64* mrow = mask + ((size_t)b * Nn + i0 + erow) * (Nn / 64);

    int w = t >> 6, lane = t & 63;
    int am = lane & 15, aq = lane >> 4;
    int c0 = w * 32;
    const f16* bbase0 = whT + (size_t)(c0 + am) * Nn + aq * 8;
    const f16* bbase1 = whT + (size_t)(c0 + 16 + am) * Nn + aq * 8;

    f32x4 acc0 = {0.f, 0.f, 0.f, 0.f}, acc1 = {0.f, 0.f, 0.f, 0.f};
    float lacc = 0.f;
    f16x8 b00 = *(const f16x8*)bbase0;
    f16x8 b01 = *(const f16x8*)(bbase0 + 32);
    f16x8 b10 = *(const f16x8*)bbase1;
    f16x8 b11 = *(const f16x8*)(bbase1 + 32);
    u64 mw = mrow[0];
    __syncthreads();

    {  // e-phase chunk 0
        f32x2 sv = *(const f32x2*)&s2_l[ejq * 2];
        float x0 = s1v + sv[0], x1 = s1v + sv[1];
        float lr0 = fmaxf(x0, ALPHA_LRELU * x0), lr1 = fmaxf(x1, ALPHA_LRELU * x1);
        float bf0 = (float)((unsigned)(mw >> (ejq * 2)) & 1u);
        float bf1 = (float)((unsigned)(mw >> (ejq * 2 + 1)) & 1u);
        float p0 = EXP2(fmaf(bf0, BIGM, fmaf(lr0, LOG2E, C0)));
        float p1 = EXP2(fmaf(bf1, BIGM, fmaf(lr1, LOG2E, C0)));
        lacc += p0 + p1;
        f16x2 pv; pv[0] = (f16)p0; pv[1] = (f16)p1;
        *(f16x2*)&P[0][erow * PSTR + ejq * 2] = pv;
    }
    u64 mwn = mrow[1];

    for (int c = 0; c < NC; ++c) {
        __syncthreads();
        int cn = (c + 1 < NC) ? c + 1 : 0;
        f16x8 n00 = *(const f16x8*)(bbase0 + (size_t)cn * 64);
        f16x8 n01 = *(const f16x8*)(bbase0 + (size_t)cn * 64 + 32);
        f16x8 n10 = *(const f16x8*)(bbase1 + (size_t)cn * 64);
        f16x8 n11 = *(const f16x8*)(bbase1 + (size_t)cn * 64 + 32);
        if (c + 1 < NC) {
            int jb = (c + 1) * 64 + ejq * 2;
            f32x2 sv = *(const f32x2*)&s2_l[jb];
            float x0 = s1v + sv[0], x1 = s1v + sv[1];
            float lr0 = fmaxf(x0, ALPHA_LRELU * x0), lr1 = fmaxf(x1, ALPHA_LRELU * x1);
            float bf0 = (float)((unsigned)(mwn >> (ejq * 2)) & 1u);
            float bf1 = (float)((unsigned)(mwn >> (ejq * 2 + 1)) & 1u);
            float p0 = EXP2(fmaf(bf0, BIGM, fmaf(lr0, LOG2E, C0)));
            float p1 = EXP2(fmaf(bf1, BIGM, fmaf(lr1, LOG2E, C0)));
            lacc += p0 + p1;
            f16x2 pv; pv[0] = (f16)p0; pv[1] = (f16)p1;
            *(f16x2*)&P[(c + 1) & 1][erow * PSTR + ejq * 2] = pv;
            mwn = mrow[(c + 2 < NC) ? c + 2 : NC - 1];
        }
        const f16* pb = &P[c & 1][am * PSTR + aq * 8];
        f16x8 a0 = *(const f16x8*)pb;
        f16x8 a1 = *(const f16x8*)(pb + 32);
        acc0 = __builtin_amdgcn_mfma_f32_16x16x32_f16(a0, b00, acc0, 0, 0, 0);
        acc0 = __builtin_amdgcn_mfma_f32_16x16x32_f16(a1, b01, acc0, 0, 0, 0);
        acc1 = __builtin_amdgcn_mfma_f32_16x16x32_f16(a0, b10, acc1, 0, 0, 0);
        acc1 = __builtin_amdgcn_mfma_f32_16x16x32_f16(a1, b11, acc1, 0, 0, 0);
        b00 = n00; b01 = n01; b10 = n10; b11 = n11;
    }

    lacc += __shfl_xor(lacc, 1);
    lacc += __shfl_xor(lacc, 2);
    lacc += __shfl_xor(lacc, 4);
    lacc += __shfl_xor(lacc, 8);
    lacc += __shfl_xor(lacc, 16);
    if ((t & 31) == 0) l_l[erow] = lacc;
    __syncthreads();

#pragma unroll
    for (int r = 0; r < 4; ++r) {
        int row = aq * 4 + r;
        float li = l_l[row];
        float v0 = acc0[r] / li, v1 = acc1[r] / li;
        v0 = v0 > 0.f ? v0 : __expf(v0) - 1.f;
        v0 = v0 > 0.f ? v0 : __expf(v0) - 1.f;
        v1 = v1 > 0.f ? v1 : __expf(v1) - 1.f;
        v1 = v1 > 0.f ? v1 : __expf(v1) - 1.f;
        size_t base = ((size_t)b * Nn + i0 + row) * Ff;
        dst[base + c0 + am] = v0;
        dst[base + c0 + 16 + am] = v1;
    }
}

// ---------------------------------------------------------------------------
extern "C" void kernel_launch(void* const* d_in, const int* in_sizes, int n_in,
                              void* d_out, int out_size, void* d_ws, size_t ws_size,
                              hipStream_t stream) {
    const float* x = (const float*)d_in[0];
    const int* adj = (const int*)d_in[1];
    const float* W_heads = (const float*)d_in[2];
    const float* a_heads = (const float*)d_in[3];
    const float* W_out = (const float*)d_in[4];
    const float* a_out = (const float*)d_in[5];
    float* out = (float*)d_out;

    float* ws = (float*)d_ws;
    const size_t M = (size_t)Bc * Nn * Ff;  // 1,048,576
    float* h_cur = ws;                      // [B,N,F] fp32
    float* h_tmp = ws + M;                  // [B,N,F] fp32
    f16* WhT = (f16*)(ws + 2 * M);          // [B,G,O,N] f16 (M elems)
    u64* mask = (u64*)(ws + 2 * M + M / 2); // B*N*N/64 words (M/4 floats)
    f16* WT = (f16*)(ws + 2 * M + M / 2 + M / 4);  // 6*F*F f16 = 196608 floats
    float* sbuf = ws + 2 * M + M / 2 + M / 4 + 3 * (size_t)Ff * Ff / 2 * 2 / 2 + 98304;
    // (layout arithmetic: WT occupies 6*256*256/2 = 196608 floats)
    sbuf = ws + 2 * M + M / 2 + M / 4 + 196608;
    const size_t SH = (size_t)Bc * Hh * Nn;  // 32768
    const size_t SO = (size_t)Bc * Nn;       // 4096
    const size_t SL = 2 * SH + 2 * SO;       // per layer

    zero_kernel<<<(3 * SL) / 256, 256, 0, stream>>>(sbuf);
    pack_kernel<<<(Bc * Nn * Nn) / 256, 256, 0, stream>>>(adj, mask);
    wt_kernel<<<dim3(Ff / 4, 6), 256, 0, stream>>>(W_heads, W_out, WT);

    for (int l = 0; l < 3; ++l) {
        const float* hin = (l == 0) ? x : h_cur;
        float* s1h = sbuf + l * SL;
        float* s2h = s1h + SH;
        float* s1o = s2h + SH;
        float* s2o = s1o + SO;

        // ---- head GAT: G=8, O=32 ----
        gemm_mfma<<<dim3((Bc * Nn) / 32, Ff / 64), 256, 0, stream>>>(
            hin, WT + (size_t)(2 * l) * Ff * Ff,
            a_heads + (size_t)l * Hh * 2 * Oo, WhT, s1h, s2h, Hh, Oo, 5);
        attn_head<<<dim3(Nn / 32, 1, Bc * Hh), 256, 0, stream>>>(
            WhT, s1h, s2h, mask, h_tmp);

        // ---- out GAT: G=1, O=F=256 ----
        gemm_mfma<<<dim3((Bc * Nn) / 32, Ff / 64), 256, 0, stream>>>(
            h_tmp, WT + (size_t)(2 * l + 1) * Ff * Ff,
            a_out + (size_t)l * 2 * Ff, WhT, s1o, s2o, 1, Ff, 8);
        float* dstp = (l == 2) ? out : h_cur;
        attn_out<<<dim3(Nn / 16, 1, Bc), 512, 0, stream>>>(
            WhT, s1o, s2o, mask, dstp);
    }
}